// Round 1
// baseline (1412.448 us; speedup 1.0000x reference)
//
#include <hip/hip_runtime.h>

// RGCN layer with skip on MI355X.
// out[n] = bias + skip_bias + x[n]@skipW^T + h[n]@rootW + sum_{e: dst=n} ew[e] * (h[src] @ rel[etype])
//
// Round 0: fp32 VALU GEMMs (no fp32 MFMA on CDNA4), h_rel materialized in d_ws,
// edge gather + f32 atomic scatter-add.

constexpr int DIM  = 128;
constexpr int BM   = 64;   // rows per block in GEMM kernels
constexpr int KC   = 32;   // K chunk staged in LDS
constexpr int BPAD = 4;    // pad B tile rows to kill 32-way bank conflict on transposed store

// ---------------------------------------------------------------------------
// out[n,f] = (bias[f] + skip_bias[f]) + sum_d x[n,d]*skipW[f,d] + sum_d h[n,d]*rootW[d,f]
// ---------------------------------------------------------------------------
__global__ __launch_bounds__(256) void base_kernel(
    const float* __restrict__ x, const float* __restrict__ h,
    const float* __restrict__ skipW, const float* __restrict__ rootW,
    const float* __restrict__ bias, const float* __restrict__ skipB,
    float* __restrict__ out, int N)
{
    __shared__ float As[BM][KC];
    __shared__ float Bs[KC][DIM + BPAD];

    const int tid = threadIdx.x;
    const int n0  = blockIdx.x * BM;
    const int f0  = (tid & 31) * 4;   // 32 col-groups of 4
    const int r0  = (tid >> 5) * 8;   // 8 row-groups of 8

    float acc[8][4] = {};

    for (int phase = 0; phase < 2; ++phase) {
        const float* __restrict__ A = phase ? h : x;
        for (int d0 = 0; d0 < DIM; d0 += KC) {
            __syncthreads();
            // stage A tile [BM][KC]
            for (int idx = tid; idx < BM * KC; idx += 256) {
                int r = idx / KC, dd = idx % KC;
                int n = n0 + r;
                As[r][dd] = (n < N) ? A[(long long)n * DIM + d0 + dd] : 0.f;
            }
            // stage B tile [KC][DIM]; phase 0 needs skipW transposed (B[d][f] = skipW[f][d])
            if (phase == 0) {
                for (int idx = tid; idx < DIM * KC; idx += 256) {
                    int f = idx / KC, dd = idx % KC;
                    Bs[dd][f] = skipW[f * DIM + d0 + dd];
                }
            } else {
                for (int idx = tid; idx < KC * DIM; idx += 256) {
                    int dd = idx / DIM, f = idx % DIM;
                    Bs[dd][f] = rootW[(d0 + dd) * DIM + f];
                }
            }
            __syncthreads();
            #pragma unroll
            for (int dd = 0; dd < KC; ++dd) {
                float a[8];
                #pragma unroll
                for (int i = 0; i < 8; ++i) a[i] = As[r0 + i][dd];  // broadcast within half-wave
                const float4 b = *reinterpret_cast<const float4*>(&Bs[dd][f0]);
                #pragma unroll
                for (int i = 0; i < 8; ++i) {
                    acc[i][0] += a[i] * b.x; acc[i][1] += a[i] * b.y;
                    acc[i][2] += a[i] * b.z; acc[i][3] += a[i] * b.w;
                }
            }
        }
    }

    float bb[4];
    #pragma unroll
    for (int j = 0; j < 4; ++j) bb[j] = bias[f0 + j] + skipB[f0 + j];
    #pragma unroll
    for (int i = 0; i < 8; ++i) {
        int n = n0 + r0 + i;
        if (n < N) {
            float4 v = make_float4(acc[i][0] + bb[0], acc[i][1] + bb[1],
                                   acc[i][2] + bb[2], acc[i][3] + bb[3]);
            *reinterpret_cast<float4*>(&out[(long long)n * DIM + f0]) = v;
        }
    }
}

// ---------------------------------------------------------------------------
// hrel[n,r,f] = sum_d h[n,d] * rel[r,d,f]     (grid.y = r)
// ---------------------------------------------------------------------------
__global__ __launch_bounds__(256) void hrel_kernel(
    const float* __restrict__ h, const float* __restrict__ rel,
    float* __restrict__ hrel, int N, int R)
{
    __shared__ float As[BM][KC];
    __shared__ float Bs[KC][DIM + BPAD];

    const int tid = threadIdx.x;
    const int n0  = blockIdx.x * BM;
    const int rr  = blockIdx.y;
    const float* __restrict__ B = rel + (size_t)rr * DIM * DIM;
    const int f0  = (tid & 31) * 4;
    const int r0  = (tid >> 5) * 8;

    float acc[8][4] = {};

    for (int d0 = 0; d0 < DIM; d0 += KC) {
        __syncthreads();
        for (int idx = tid; idx < BM * KC; idx += 256) {
            int r = idx / KC, dd = idx % KC;
            int n = n0 + r;
            As[r][dd] = (n < N) ? h[(long long)n * DIM + d0 + dd] : 0.f;
        }
        for (int idx = tid; idx < KC * DIM; idx += 256) {
            int dd = idx / DIM, f = idx % DIM;
            Bs[dd][f] = B[(d0 + dd) * DIM + f];
        }
        __syncthreads();
        #pragma unroll
        for (int dd = 0; dd < KC; ++dd) {
            float a[8];
            #pragma unroll
            for (int i = 0; i < 8; ++i) a[i] = As[r0 + i][dd];
            const float4 b = *reinterpret_cast<const float4*>(&Bs[dd][f0]);
            #pragma unroll
            for (int i = 0; i < 8; ++i) {
                acc[i][0] += a[i] * b.x; acc[i][1] += a[i] * b.y;
                acc[i][2] += a[i] * b.z; acc[i][3] += a[i] * b.w;
            }
        }
    }

    #pragma unroll
    for (int i = 0; i < 8; ++i) {
        int n = n0 + r0 + i;
        if (n < N) {
            float4 v = make_float4(acc[i][0], acc[i][1], acc[i][2], acc[i][3]);
            *reinterpret_cast<float4*>(&hrel[((long long)n * R + rr) * DIM + f0]) = v;
        }
    }
}

// ---------------------------------------------------------------------------
// per edge: out[dst] += ew * hrel[src, etype]   (half-wave = 32 lanes per edge)
// ---------------------------------------------------------------------------
__global__ __launch_bounds__(256) void edge_kernel(
    const int* __restrict__ ei, const int* __restrict__ et,
    const float* __restrict__ ew, const float* __restrict__ hrel,
    float* __restrict__ out, int E, int R)
{
    const int tid  = threadIdx.x;
    const int lane = tid & 31;
    const long long e = (long long)blockIdx.x * 8 + (tid >> 5);
    if (e >= E) return;

    const int   src = ei[e];
    const int   dst = ei[(long long)E + e];
    const int   r   = et[e];
    const float w   = ew[e];

    const float4 v = reinterpret_cast<const float4*>(
        hrel + ((long long)src * R + r) * DIM)[lane];

    float* o = out + (long long)dst * DIM + lane * 4;
    atomicAdd(o + 0, v.x * w);
    atomicAdd(o + 1, v.y * w);
    atomicAdd(o + 2, v.z * w);
    atomicAdd(o + 3, v.w * w);
}

// ---------------------------------------------------------------------------
// fallback (no workspace): per-edge direct matvec, one wave per edge. Slow but correct.
// ---------------------------------------------------------------------------
__global__ __launch_bounds__(256) void edge_direct_kernel(
    const int* __restrict__ ei, const int* __restrict__ et,
    const float* __restrict__ ew, const float* __restrict__ h,
    const float* __restrict__ rel, float* __restrict__ out, int E)
{
    const int wid  = threadIdx.x >> 6;
    const int lane = threadIdx.x & 63;
    const long long e = (long long)blockIdx.x * 4 + wid;
    if (e >= E) return;

    const int   src = ei[e];
    const int   dst = ei[(long long)E + e];
    const int   r   = et[e];
    const float w   = ew[e];

    const float* __restrict__ hrow = h + (long long)src * DIM;
    const float* __restrict__ W    = rel + (size_t)r * DIM * DIM;

    float acc0 = 0.f, acc1 = 0.f;
    #pragma unroll 8
    for (int d = 0; d < DIM; ++d) {
        float hv = hrow[d];
        acc0 += hv * W[d * DIM + lane];
        acc1 += hv * W[d * DIM + lane + 64];
    }
    atomicAdd(&out[(long long)dst * DIM + lane],      acc0 * w);
    atomicAdd(&out[(long long)dst * DIM + lane + 64], acc1 * w);
}

// ---------------------------------------------------------------------------
extern "C" void kernel_launch(void* const* d_in, const int* in_sizes, int n_in,
                              void* d_out, int out_size, void* d_ws, size_t ws_size,
                              hipStream_t stream)
{
    const float* x     = (const float*)d_in[0];
    const float* h     = (const float*)d_in[1];
    const int*   ei    = (const int*)  d_in[2];
    const int*   et    = (const int*)  d_in[3];
    const float* ew    = (const float*)d_in[4];
    const float* rel   = (const float*)d_in[5];
    const float* rootW = (const float*)d_in[6];
    const float* bias  = (const float*)d_in[7];
    const float* skipW = (const float*)d_in[8];
    const float* skipB = (const float*)d_in[9];
    float* out = (float*)d_out;

    const int N = in_sizes[0] / DIM;           // 50000
    const int E = in_sizes[3];                 // 600000
    const int R = in_sizes[5] / (DIM * DIM);   // 8

    // 1) out = bias + skip_bias + x@skipW^T + h@rootW   (overwrites poisoned d_out)
    base_kernel<<<dim3((N + BM - 1) / BM), 256, 0, stream>>>(
        x, h, skipW, rootW, bias, skipB, out, N);

    const size_t need = (size_t)N * R * DIM * sizeof(float);
    if (ws_size >= need) {
        float* hrel = (float*)d_ws;
        // 2) hrel[n,r,:] = h[n] @ rel[r]
        hrel_kernel<<<dim3((N + BM - 1) / BM, R), 256, 0, stream>>>(h, rel, hrel, N, R);
        // 3) scatter: out[dst] += ew * hrel[src, etype]
        edge_kernel<<<dim3((E + 7) / 8), 256, 0, stream>>>(ei, et, ew, hrel, out, E, R);
    } else {
        edge_direct_kernel<<<dim3((E + 3) / 4), 256, 0, stream>>>(ei, et, ew, h, rel, out, E);
    }
}

// Round 2
// 653.387 us; speedup vs baseline: 2.1617x; 2.1617x over previous
//
#include <hip/hip_runtime.h>

// RGCN layer with skip on MI355X.
// out[n] = bias + skip_bias + x[n]@skipW^T + h[n]@rootW + sum_{e: dst=n} ew[e]*(h[src]@rel[etype])
//
// Round 1: aggregate-then-transform. CSR-by-dst -> per-node relation-bucket
// accumulation S[n,r,:] (no float atomics) -> one fused GEMM out += S @ rel_flat.

constexpr int DIM  = 128;
constexpr int BM   = 64;
constexpr int KC   = 32;
constexpr int BPAD = 4;

// ---------------------------------------------------------------------------
// out[n,f] = (bias[f]+skipB[f]) + sum_d x[n,d]*skipW[f,d] + sum_d h[n,d]*rootW[d,f]
// ---------------------------------------------------------------------------
__global__ __launch_bounds__(256) void base_kernel(
    const float* __restrict__ x, const float* __restrict__ h,
    const float* __restrict__ skipW, const float* __restrict__ rootW,
    const float* __restrict__ bias, const float* __restrict__ skipB,
    float* __restrict__ out, int N)
{
    __shared__ float As[BM][KC];
    __shared__ float Bs[KC][DIM + BPAD];

    const int tid = threadIdx.x;
    const int n0  = blockIdx.x * BM;
    const int f0  = (tid & 31) * 4;
    const int r0  = (tid >> 5) * 8;

    float acc[8][4] = {};

    for (int phase = 0; phase < 2; ++phase) {
        const float* __restrict__ A = phase ? h : x;
        for (int d0 = 0; d0 < DIM; d0 += KC) {
            __syncthreads();
            for (int idx = tid; idx < BM * KC; idx += 256) {
                int r = idx / KC, dd = idx % KC;
                int n = n0 + r;
                As[r][dd] = (n < N) ? A[(long long)n * DIM + d0 + dd] : 0.f;
            }
            if (phase == 0) {
                for (int idx = tid; idx < DIM * KC; idx += 256) {
                    int f = idx / KC, dd = idx % KC;
                    Bs[dd][f] = skipW[f * DIM + d0 + dd];
                }
            } else {
                for (int idx = tid; idx < KC * DIM; idx += 256) {
                    int dd = idx / DIM, f = idx % DIM;
                    Bs[dd][f] = rootW[(d0 + dd) * DIM + f];
                }
            }
            __syncthreads();
            #pragma unroll
            for (int dd = 0; dd < KC; ++dd) {
                float a[8];
                #pragma unroll
                for (int i = 0; i < 8; ++i) a[i] = As[r0 + i][dd];
                const float4 b = *reinterpret_cast<const float4*>(&Bs[dd][f0]);
                #pragma unroll
                for (int i = 0; i < 8; ++i) {
                    acc[i][0] += a[i] * b.x; acc[i][1] += a[i] * b.y;
                    acc[i][2] += a[i] * b.z; acc[i][3] += a[i] * b.w;
                }
            }
        }
    }

    float bb[4];
    #pragma unroll
    for (int j = 0; j < 4; ++j) bb[j] = bias[f0 + j] + skipB[f0 + j];
    #pragma unroll
    for (int i = 0; i < 8; ++i) {
        int n = n0 + r0 + i;
        if (n < N) {
            float4 v = make_float4(acc[i][0] + bb[0], acc[i][1] + bb[1],
                                   acc[i][2] + bb[2], acc[i][3] + bb[3]);
            *reinterpret_cast<float4*>(&out[(long long)n * DIM + f0]) = v;
        }
    }
}

// ---------------------------------------------------------------------------
// CSR build
// ---------------------------------------------------------------------------
__global__ __launch_bounds__(256) void zero_i32_kernel(int* __restrict__ p, int n)
{
    int i = blockIdx.x * 256 + threadIdx.x;
    if (i < n) p[i] = 0;
}

__global__ __launch_bounds__(256) void hist_kernel(
    const int* __restrict__ ei, int* __restrict__ counts, int E)
{
    int e = blockIdx.x * 256 + threadIdx.x;
    if (e < E) atomicAdd(&counts[ei[(long long)E + e]], 1);
}

// single-block exclusive scan of counts[N] -> offsets[N+1]; also cursor = offsets.
// counts and cursor alias the same array (read-before-write per element).
__global__ __launch_bounds__(1024) void scan_kernel(
    const int* __restrict__ counts, int* __restrict__ offsets,
    int* __restrict__ cursor, int N, int E)
{
    __shared__ int sh[1024];
    const int t  = threadIdx.x;
    const int CH = (N + 1023) / 1024;

    int s = 0;
    for (int j = 0; j < CH; ++j) {
        int idx = t * CH + j;
        if (idx < N) s += counts[idx];
    }
    sh[t] = s;
    __syncthreads();
    for (int off = 1; off < 1024; off <<= 1) {
        int v = (t >= off) ? sh[t - off] : 0;
        __syncthreads();
        sh[t] += v;
        __syncthreads();
    }
    int base = sh[t] - s;   // exclusive prefix of this thread's chunk
    for (int j = 0; j < CH; ++j) {
        int idx = t * CH + j;
        if (idx < N) {
            int c = counts[idx];       // read BEFORE aliased write
            offsets[idx] = base;
            cursor[idx]  = base;
            base += c;
        }
    }
    if (t == 1023) offsets[N] = E;
}

__global__ __launch_bounds__(256) void scatter_kernel(
    const int* __restrict__ ei, int* __restrict__ cursor,
    int* __restrict__ perm, int E)
{
    int e = blockIdx.x * 256 + threadIdx.x;
    if (e < E) {
        int pos = atomicAdd(&cursor[ei[(long long)E + e]], 1);
        perm[pos] = e;
    }
}

// ---------------------------------------------------------------------------
// one wave per dst node: S[n,r,:] = sum_{e in bucket(n), type=r} ew[e]*h[src[e],:]
// R==8 specialization; predicated bucket select (no runtime register indexing).
// ---------------------------------------------------------------------------
__global__ __launch_bounds__(256) void accum_kernel(
    const int* __restrict__ ei, const int* __restrict__ et,
    const float* __restrict__ ew, const float* __restrict__ h,
    const int* __restrict__ offsets, const int* __restrict__ perm,
    float* __restrict__ S, int N, int E)
{
    const int n    = blockIdx.x * 4 + (threadIdx.x >> 6);
    const int lane = threadIdx.x & 63;
    if (n >= N) return;

    const int start = offsets[n];
    const int end   = offsets[n + 1];

    float2 acc[8];
    #pragma unroll
    for (int rr = 0; rr < 8; ++rr) acc[rr] = make_float2(0.f, 0.f);

    for (int o = start; o < end; ++o) {
        const int   e   = perm[o];
        const int   src = ei[e];
        const int   r   = et[e];
        const float w   = ew[e];
        const float2 hv = *reinterpret_cast<const float2*>(
            h + (long long)src * DIM + lane * 2);
        #pragma unroll
        for (int rr = 0; rr < 8; ++rr) {
            const float m = (rr == r) ? w : 0.f;
            acc[rr].x += m * hv.x;
            acc[rr].y += m * hv.y;
        }
    }

    #pragma unroll
    for (int rr = 0; rr < 8; ++rr) {
        *reinterpret_cast<float2*>(
            S + ((long long)n * 8 + rr) * DIM + lane * 2) = acc[rr];
    }
}

// ---------------------------------------------------------------------------
// out[n,f] += sum_{k<1024} S[n,k] * relF[k,f]   (relF = rel_weight viewed [R*D, D])
// ---------------------------------------------------------------------------
__global__ __launch_bounds__(256) void fuse_gemm_kernel(
    const float* __restrict__ S, const float* __restrict__ relF,
    float* __restrict__ out, int N, int K)
{
    __shared__ float As[BM][36];            // 36 = KC + 4 (pad: 16B-aligned rows, 2-way max)
    __shared__ float Bs[KC][DIM + BPAD];

    const int tid = threadIdx.x;
    const int n0  = blockIdx.x * BM;
    const int f0  = (tid & 15) * 4;         // cols f0..f0+3 and f0+64..f0+67
    const int r0  = (tid >> 4) * 4;         // 16 row groups x 4 rows = 64

    float acc[4][8] = {};

    for (int d0 = 0; d0 < K; d0 += KC) {
        __syncthreads();
        // stage A: 64 x 32 floats = 512 float4s
        for (int idx = tid; idx < 512; idx += 256) {
            int r = idx >> 3, q = idx & 7;
            int n = n0 + r;
            float4 v = (n < N)
                ? *reinterpret_cast<const float4*>(&S[(long long)n * K + d0 + q * 4])
                : make_float4(0.f, 0.f, 0.f, 0.f);
            *reinterpret_cast<float4*>(&As[r][q * 4]) = v;
        }
        // stage B: 32 x 128 floats = 1024 float4s
        for (int idx = tid; idx < 1024; idx += 256) {
            int dd = idx >> 5, q = idx & 31;
            float4 v = *reinterpret_cast<const float4*>(&relF[(long long)(d0 + dd) * DIM + q * 4]);
            *reinterpret_cast<float4*>(&Bs[dd][q * 4]) = v;
        }
        __syncthreads();
        #pragma unroll
        for (int dd = 0; dd < KC; ++dd) {
            float a[4];
            #pragma unroll
            for (int i = 0; i < 4; ++i) a[i] = As[r0 + i][dd];
            const float4 b0 = *reinterpret_cast<const float4*>(&Bs[dd][f0]);
            const float4 b1 = *reinterpret_cast<const float4*>(&Bs[dd][f0 + 64]);
            #pragma unroll
            for (int i = 0; i < 4; ++i) {
                acc[i][0] += a[i] * b0.x; acc[i][1] += a[i] * b0.y;
                acc[i][2] += a[i] * b0.z; acc[i][3] += a[i] * b0.w;
                acc[i][4] += a[i] * b1.x; acc[i][5] += a[i] * b1.y;
                acc[i][6] += a[i] * b1.z; acc[i][7] += a[i] * b1.w;
            }
        }
    }

    #pragma unroll
    for (int i = 0; i < 4; ++i) {
        int n = n0 + r0 + i;
        if (n < N) {
            float4* p0 = reinterpret_cast<float4*>(&out[(long long)n * DIM + f0]);
            float4* p1 = reinterpret_cast<float4*>(&out[(long long)n * DIM + f0 + 64]);
            float4 o0 = *p0, o1 = *p1;
            o0.x += acc[i][0]; o0.y += acc[i][1]; o0.z += acc[i][2]; o0.w += acc[i][3];
            o1.x += acc[i][4]; o1.y += acc[i][5]; o1.z += acc[i][6]; o1.w += acc[i][7];
            *p0 = o0; *p1 = o1;
        }
    }
}

// ---------------------------------------------------------------------------
// fallback kernels (round 0) in case ws is too small or R != 8
// ---------------------------------------------------------------------------
__global__ __launch_bounds__(256) void hrel_kernel(
    const float* __restrict__ h, const float* __restrict__ rel,
    float* __restrict__ hrel, int N, int R)
{
    __shared__ float As[BM][KC];
    __shared__ float Bs[KC][DIM + BPAD];

    const int tid = threadIdx.x;
    const int n0  = blockIdx.x * BM;
    const int rr  = blockIdx.y;
    const float* __restrict__ B = rel + (size_t)rr * DIM * DIM;
    const int f0  = (tid & 31) * 4;
    const int r0  = (tid >> 5) * 8;

    float acc[8][4] = {};

    for (int d0 = 0; d0 < DIM; d0 += KC) {
        __syncthreads();
        for (int idx = tid; idx < BM * KC; idx += 256) {
            int r = idx / KC, dd = idx % KC;
            int n = n0 + r;
            As[r][dd] = (n < N) ? h[(long long)n * DIM + d0 + dd] : 0.f;
        }
        for (int idx = tid; idx < KC * DIM; idx += 256) {
            int dd = idx / DIM, f = idx % DIM;
            Bs[dd][f] = B[(d0 + dd) * DIM + f];
        }
        __syncthreads();
        #pragma unroll
        for (int dd = 0; dd < KC; ++dd) {
            float a[8];
            #pragma unroll
            for (int i = 0; i < 8; ++i) a[i] = As[r0 + i][dd];
            const float4 b = *reinterpret_cast<const float4*>(&Bs[dd][f0]);
            #pragma unroll
            for (int i = 0; i < 8; ++i) {
                acc[i][0] += a[i] * b.x; acc[i][1] += a[i] * b.y;
                acc[i][2] += a[i] * b.z; acc[i][3] += a[i] * b.w;
            }
        }
    }

    #pragma unroll
    for (int i = 0; i < 8; ++i) {
        int n = n0 + r0 + i;
        if (n < N) {
            float4 v = make_float4(acc[i][0], acc[i][1], acc[i][2], acc[i][3]);
            *reinterpret_cast<float4*>(&hrel[((long long)n * R + rr) * DIM + f0]) = v;
        }
    }
}

__global__ __launch_bounds__(256) void edge_kernel(
    const int* __restrict__ ei, const int* __restrict__ et,
    const float* __restrict__ ew, const float* __restrict__ hrel,
    float* __restrict__ out, int E, int R)
{
    const int tid  = threadIdx.x;
    const int lane = tid & 31;
    const long long e = (long long)blockIdx.x * 8 + (tid >> 5);
    if (e >= E) return;

    const int   src = ei[e];
    const int   dst = ei[(long long)E + e];
    const int   r   = et[e];
    const float w   = ew[e];

    const float4 v = reinterpret_cast<const float4*>(
        hrel + ((long long)src * R + r) * DIM)[lane];

    float* o = out + (long long)dst * DIM + lane * 4;
    atomicAdd(o + 0, v.x * w);
    atomicAdd(o + 1, v.y * w);
    atomicAdd(o + 2, v.z * w);
    atomicAdd(o + 3, v.w * w);
}

__global__ __launch_bounds__(256) void edge_direct_kernel(
    const int* __restrict__ ei, const int* __restrict__ et,
    const float* __restrict__ ew, const float* __restrict__ h,
    const float* __restrict__ rel, float* __restrict__ out, int E)
{
    const int wid  = threadIdx.x >> 6;
    const int lane = threadIdx.x & 63;
    const long long e = (long long)blockIdx.x * 4 + wid;
    if (e >= E) return;

    const int   src = ei[e];
    const int   dst = ei[(long long)E + e];
    const int   r   = et[e];
    const float w   = ew[e];

    const float* __restrict__ hrow = h + (long long)src * DIM;
    const float* __restrict__ W    = rel + (size_t)r * DIM * DIM;

    float acc0 = 0.f, acc1 = 0.f;
    #pragma unroll 8
    for (int d = 0; d < DIM; ++d) {
        float hv = hrow[d];
        acc0 += hv * W[d * DIM + lane];
        acc1 += hv * W[d * DIM + lane + 64];
    }
    atomicAdd(&out[(long long)dst * DIM + lane],      acc0 * w);
    atomicAdd(&out[(long long)dst * DIM + lane + 64], acc1 * w);
}

// ---------------------------------------------------------------------------
extern "C" void kernel_launch(void* const* d_in, const int* in_sizes, int n_in,
                              void* d_out, int out_size, void* d_ws, size_t ws_size,
                              hipStream_t stream)
{
    const float* x     = (const float*)d_in[0];
    const float* h     = (const float*)d_in[1];
    const int*   ei    = (const int*)  d_in[2];
    const int*   et    = (const int*)  d_in[3];
    const float* ew    = (const float*)d_in[4];
    const float* rel   = (const float*)d_in[5];
    const float* rootW = (const float*)d_in[6];
    const float* bias  = (const float*)d_in[7];
    const float* skipW = (const float*)d_in[8];
    const float* skipB = (const float*)d_in[9];
    float* out = (float*)d_out;

    const int N = in_sizes[0] / DIM;           // 50000
    const int E = in_sizes[3];                 // 600000
    const int R = in_sizes[5] / (DIM * DIM);   // 8

    // 1) out = bias + skip_bias + x@skipW^T + h@rootW
    base_kernel<<<dim3((N + BM - 1) / BM), 256, 0, stream>>>(
        x, h, skipW, rootW, bias, skipB, out, N);

    const size_t S_elems  = (size_t)N * 8 * DIM;
    const size_t need_new = S_elems * sizeof(float)
                          + ((size_t)(N + 1) + N + E) * sizeof(int);

    if (R == 8 && ws_size >= need_new) {
        float* S       = (float*)d_ws;
        int*   offsets = (int*)(S + S_elems);        // N+1
        int*   cursor  = offsets + (N + 1);          // N (aliases counts)
        int*   perm    = cursor + N;                 // E

        zero_i32_kernel<<<dim3((N + 255) / 256), 256, 0, stream>>>(cursor, N);
        hist_kernel<<<dim3((E + 255) / 256), 256, 0, stream>>>(ei, cursor, E);
        scan_kernel<<<1, 1024, 0, stream>>>(cursor, offsets, cursor, N, E);
        scatter_kernel<<<dim3((E + 255) / 256), 256, 0, stream>>>(ei, cursor, perm, E);
        accum_kernel<<<dim3((N + 3) / 4), 256, 0, stream>>>(
            ei, et, ew, h, offsets, perm, S, N, E);
        fuse_gemm_kernel<<<dim3((N + BM - 1) / BM), 256, 0, stream>>>(
            S, rel, out, N, 8 * DIM);
    } else if (ws_size >= (size_t)N * R * DIM * sizeof(float)) {
        float* hrel = (float*)d_ws;
        hrel_kernel<<<dim3((N + BM - 1) / BM, R), 256, 0, stream>>>(h, rel, hrel, N, R);
        edge_kernel<<<dim3((E + 7) / 8), 256, 0, stream>>>(ei, et, ew, hrel, out, E, R);
    } else {
        edge_direct_kernel<<<dim3((E + 3) / 4), 256, 0, stream>>>(ei, et, ew, h, rel, out, E);
    }
}

// Round 3
// 648.904 us; speedup vs baseline: 2.1767x; 1.0069x over previous
//
#include <hip/hip_runtime.h>

// RGCN layer with skip on MI355X.
// out[n] = bias + skip_bias + x[n]@skipW^T + h[n]@rootW + sum_{e: dst=n} ew[e]*(h[src]@rel[etype])
//
// Round 1: aggregate-then-transform. CSR-by-dst -> per-node relation-bucket
// accumulation S[n,r,:] (no float atomics) -> one fused GEMM out += S @ rel_flat.

constexpr int DIM  = 128;
constexpr int BM   = 64;
constexpr int KC   = 32;
constexpr int BPAD = 4;

// ---------------------------------------------------------------------------
// out[n,f] = (bias[f]+skipB[f]) + sum_d x[n,d]*skipW[f,d] + sum_d h[n,d]*rootW[d,f]
// ---------------------------------------------------------------------------
__global__ __launch_bounds__(256) void base_kernel(
    const float* __restrict__ x, const float* __restrict__ h,
    const float* __restrict__ skipW, const float* __restrict__ rootW,
    const float* __restrict__ bias, const float* __restrict__ skipB,
    float* __restrict__ out, int N)
{
    __shared__ float As[BM][KC];
    __shared__ float Bs[KC][DIM + BPAD];

    const int tid = threadIdx.x;
    const int n0  = blockIdx.x * BM;
    const int f0  = (tid & 31) * 4;
    const int r0  = (tid >> 5) * 8;

    float acc[8][4] = {};

    for (int phase = 0; phase < 2; ++phase) {
        const float* __restrict__ A = phase ? h : x;
        for (int d0 = 0; d0 < DIM; d0 += KC) {
            __syncthreads();
            for (int idx = tid; idx < BM * KC; idx += 256) {
                int r = idx / KC, dd = idx % KC;
                int n = n0 + r;
                As[r][dd] = (n < N) ? A[(long long)n * DIM + d0 + dd] : 0.f;
            }
            if (phase == 0) {
                for (int idx = tid; idx < DIM * KC; idx += 256) {
                    int f = idx / KC, dd = idx % KC;
                    Bs[dd][f] = skipW[f * DIM + d0 + dd];
                }
            } else {
                for (int idx = tid; idx < KC * DIM; idx += 256) {
                    int dd = idx / DIM, f = idx % DIM;
                    Bs[dd][f] = rootW[(d0 + dd) * DIM + f];
                }
            }
            __syncthreads();
            #pragma unroll
            for (int dd = 0; dd < KC; ++dd) {
                float a[8];
                #pragma unroll
                for (int i = 0; i < 8; ++i) a[i] = As[r0 + i][dd];
                const float4 b = *reinterpret_cast<const float4*>(&Bs[dd][f0]);
                #pragma unroll
                for (int i = 0; i < 8; ++i) {
                    acc[i][0] += a[i] * b.x; acc[i][1] += a[i] * b.y;
                    acc[i][2] += a[i] * b.z; acc[i][3] += a[i] * b.w;
                }
            }
        }
    }

    float bb[4];
    #pragma unroll
    for (int j = 0; j < 4; ++j) bb[j] = bias[f0 + j] + skipB[f0 + j];
    #pragma unroll
    for (int i = 0; i < 8; ++i) {
        int n = n0 + r0 + i;
        if (n < N) {
            float4 v = make_float4(acc[i][0] + bb[0], acc[i][1] + bb[1],
                                   acc[i][2] + bb[2], acc[i][3] + bb[3]);
            *reinterpret_cast<float4*>(&out[(long long)n * DIM + f0]) = v;
        }
    }
}

// ---------------------------------------------------------------------------
// CSR build
// ---------------------------------------------------------------------------
__global__ __launch_bounds__(256) void zero_i32_kernel(int* __restrict__ p, int n)
{
    int i = blockIdx.x * 256 + threadIdx.x;
    if (i < n) p[i] = 0;
}

__global__ __launch_bounds__(256) void hist_kernel(
    const int* __restrict__ ei, int* __restrict__ counts, int E)
{
    int e = blockIdx.x * 256 + threadIdx.x;
    if (e < E) atomicAdd(&counts[ei[(long long)E + e]], 1);
}

// single-block exclusive scan of counts[N] -> offsets[N+1]; also cursor = offsets.
// counts and cursor alias the same array (read-before-write per element).
__global__ __launch_bounds__(1024) void scan_kernel(
    const int* __restrict__ counts, int* __restrict__ offsets,
    int* __restrict__ cursor, int N, int E)
{
    __shared__ int sh[1024];
    const int t  = threadIdx.x;
    const int CH = (N + 1023) / 1024;

    int s = 0;
    for (int j = 0; j < CH; ++j) {
        int idx = t * CH + j;
        if (idx < N) s += counts[idx];
    }
    sh[t] = s;
    __syncthreads();
    for (int off = 1; off < 1024; off <<= 1) {
        int v = (t >= off) ? sh[t - off] : 0;
        __syncthreads();
        sh[t] += v;
        __syncthreads();
    }
    int base = sh[t] - s;   // exclusive prefix of this thread's chunk
    for (int j = 0; j < CH; ++j) {
        int idx = t * CH + j;
        if (idx < N) {
            int c = counts[idx];       // read BEFORE aliased write
            offsets[idx] = base;
            cursor[idx]  = base;
            base += c;
        }
    }
    if (t == 1023) offsets[N] = E;
}

__global__ __launch_bounds__(256) void scatter_kernel(
    const int* __restrict__ ei, int* __restrict__ cursor,
    int* __restrict__ perm, int E)
{
    int e = blockIdx.x * 256 + threadIdx.x;
    if (e < E) {
        int pos = atomicAdd(&cursor[ei[(long long)E + e]], 1);
        perm[pos] = e;
    }
}

// ---------------------------------------------------------------------------
// one wave per dst node: S[n,r,:] = sum_{e in bucket(n), type=r} ew[e]*h[src[e],:]
// R==8 specialization; predicated bucket select (no runtime register indexing).
// ---------------------------------------------------------------------------
__global__ __launch_bounds__(256) void accum_kernel(
    const int* __restrict__ ei, const int* __restrict__ et,
    const float* __restrict__ ew, const float* __restrict__ h,
    const int* __restrict__ offsets, const int* __restrict__ perm,
    float* __restrict__ S, int N, int E)
{
    const int n    = blockIdx.x * 4 + (threadIdx.x >> 6);
    const int lane = threadIdx.x & 63;
    if (n >= N) return;

    const int start = offsets[n];
    const int end   = offsets[n + 1];

    float2 acc[8];
    #pragma unroll
    for (int rr = 0; rr < 8; ++rr) acc[rr] = make_float2(0.f, 0.f);

    for (int o = start; o < end; ++o) {
        const int   e   = perm[o];
        const int   src = ei[e];
        const int   r   = et[e];
        const float w   = ew[e];
        const float2 hv = *reinterpret_cast<const float2*>(
            h + (long long)src * DIM + lane * 2);
        #pragma unroll
        for (int rr = 0; rr < 8; ++rr) {
            const float m = (rr == r) ? w : 0.f;
            acc[rr].x += m * hv.x;
            acc[rr].y += m * hv.y;
        }
    }

    #pragma unroll
    for (int rr = 0; rr < 8; ++rr) {
        *reinterpret_cast<float2*>(
            S + ((long long)n * 8 + rr) * DIM + lane * 2) = acc[rr];
    }
}

// ---------------------------------------------------------------------------
// out[n,f] += sum_{k<1024} S[n,k] * relF[k,f]   (relF = rel_weight viewed [R*D, D])
// ---------------------------------------------------------------------------
__global__ __launch_bounds__(256) void fuse_gemm_kernel(
    const float* __restrict__ S, const float* __restrict__ relF,
    float* __restrict__ out, int N, int K)
{
    __shared__ float As[BM][36];            // 36 = KC + 4 (pad: 16B-aligned rows, 2-way max)
    __shared__ float Bs[KC][DIM + BPAD];

    const int tid = threadIdx.x;
    const int n0  = blockIdx.x * BM;
    const int f0  = (tid & 15) * 4;         // cols f0..f0+3 and f0+64..f0+67
    const int r0  = (tid >> 4) * 4;         // 16 row groups x 4 rows = 64

    float acc[4][8] = {};

    for (int d0 = 0; d0 < K; d0 += KC) {
        __syncthreads();
        // stage A: 64 x 32 floats = 512 float4s
        for (int idx = tid; idx < 512; idx += 256) {
            int r = idx >> 3, q = idx & 7;
            int n = n0 + r;
            float4 v = (n < N)
                ? *reinterpret_cast<const float4*>(&S[(long long)n * K + d0 + q * 4])
                : make_float4(0.f, 0.f, 0.f, 0.f);
            *reinterpret_cast<float4*>(&As[r][q * 4]) = v;
        }
        // stage B: 32 x 128 floats = 1024 float4s
        for (int idx = tid; idx < 1024; idx += 256) {
            int dd = idx >> 5, q = idx & 31;
            float4 v = *reinterpret_cast<const float4*>(&relF[(long long)(d0 + dd) * DIM + q * 4]);
            *reinterpret_cast<float4*>(&Bs[dd][q * 4]) = v;
        }
        __syncthreads();
        #pragma unroll
        for (int dd = 0; dd < KC; ++dd) {
            float a[4];
            #pragma unroll
            for (int i = 0; i < 4; ++i) a[i] = As[r0 + i][dd];
            const float4 b0 = *reinterpret_cast<const float4*>(&Bs[dd][f0]);
            const float4 b1 = *reinterpret_cast<const float4*>(&Bs[dd][f0 + 64]);
            #pragma unroll
            for (int i = 0; i < 4; ++i) {
                acc[i][0] += a[i] * b0.x; acc[i][1] += a[i] * b0.y;
                acc[i][2] += a[i] * b0.z; acc[i][3] += a[i] * b0.w;
                acc[i][4] += a[i] * b1.x; acc[i][5] += a[i] * b1.y;
                acc[i][6] += a[i] * b1.z; acc[i][7] += a[i] * b1.w;
            }
        }
    }

    #pragma unroll
    for (int i = 0; i < 4; ++i) {
        int n = n0 + r0 + i;
        if (n < N) {
            float4* p0 = reinterpret_cast<float4*>(&out[(long long)n * DIM + f0]);
            float4* p1 = reinterpret_cast<float4*>(&out[(long long)n * DIM + f0 + 64]);
            float4 o0 = *p0, o1 = *p1;
            o0.x += acc[i][0]; o0.y += acc[i][1]; o0.z += acc[i][2]; o0.w += acc[i][3];
            o1.x += acc[i][4]; o1.y += acc[i][5]; o1.z += acc[i][6]; o1.w += acc[i][7];
            *p0 = o0; *p1 = o1;
        }
    }
}

// ---------------------------------------------------------------------------
// fallback kernels (round 0) in case ws is too small or R != 8
// ---------------------------------------------------------------------------
__global__ __launch_bounds__(256) void hrel_kernel(
    const float* __restrict__ h, const float* __restrict__ rel,
    float* __restrict__ hrel, int N, int R)
{
    __shared__ float As[BM][KC];
    __shared__ float Bs[KC][DIM + BPAD];

    const int tid = threadIdx.x;
    const int n0  = blockIdx.x * BM;
    const int rr  = blockIdx.y;
    const float* __restrict__ B = rel + (size_t)rr * DIM * DIM;
    const int f0  = (tid & 31) * 4;
    const int r0  = (tid >> 5) * 8;

    float acc[8][4] = {};

    for (int d0 = 0; d0 < DIM; d0 += KC) {
        __syncthreads();
        for (int idx = tid; idx < BM * KC; idx += 256) {
            int r = idx / KC, dd = idx % KC;
            int n = n0 + r;
            As[r][dd] = (n < N) ? h[(long long)n * DIM + d0 + dd] : 0.f;
        }
        for (int idx = tid; idx < KC * DIM; idx += 256) {
            int dd = idx / DIM, f = idx % DIM;
            Bs[dd][f] = B[(d0 + dd) * DIM + f];
        }
        __syncthreads();
        #pragma unroll
        for (int dd = 0; dd < KC; ++dd) {
            float a[8];
            #pragma unroll
            for (int i = 0; i < 8; ++i) a[i] = As[r0 + i][dd];
            const float4 b = *reinterpret_cast<const float4*>(&Bs[dd][f0]);
            #pragma unroll
            for (int i = 0; i < 8; ++i) {
                acc[i][0] += a[i] * b.x; acc[i][1] += a[i] * b.y;
                acc[i][2] += a[i] * b.z; acc[i][3] += a[i] * b.w;
            }
        }
    }

    #pragma unroll
    for (int i = 0; i < 8; ++i) {
        int n = n0 + r0 + i;
        if (n < N) {
            float4 v = make_float4(acc[i][0], acc[i][1], acc[i][2], acc[i][3]);
            *reinterpret_cast<float4*>(&hrel[((long long)n * R + rr) * DIM + f0]) = v;
        }
    }
}

__global__ __launch_bounds__(256) void edge_kernel(
    const int* __restrict__ ei, const int* __restrict__ et,
    const float* __restrict__ ew, const float* __restrict__ hrel,
    float* __restrict__ out, int E, int R)
{
    const int tid  = threadIdx.x;
    const int lane = tid & 31;
    const long long e = (long long)blockIdx.x * 8 + (tid >> 5);
    if (e >= E) return;

    const int   src = ei[e];
    const int   dst = ei[(long long)E + e];
    const int   r   = et[e];
    const float w   = ew[e];

    const float4 v = reinterpret_cast<const float4*>(
        hrel + ((long long)src * R + r) * DIM)[lane];

    float* o = out + (long long)dst * DIM + lane * 4;
    atomicAdd(o + 0, v.x * w);
    atomicAdd(o + 1, v.y * w);
    atomicAdd(o + 2, v.z * w);
    atomicAdd(o + 3, v.w * w);
}

__global__ __launch_bounds__(256) void edge_direct_kernel(
    const int* __restrict__ ei, const int* __restrict__ et,
    const float* __restrict__ ew, const float* __restrict__ h,
    const float* __restrict__ rel, float* __restrict__ out, int E)
{
    const int wid  = threadIdx.x >> 6;
    const int lane = threadIdx.x & 63;
    const long long e = (long long)blockIdx.x * 4 + wid;
    if (e >= E) return;

    const int   src = ei[e];
    const int   dst = ei[(long long)E + e];
    const int   r   = et[e];
    const float w   = ew[e];

    const float* __restrict__ hrow = h + (long long)src * DIM;
    const float* __restrict__ W    = rel + (size_t)r * DIM * DIM;

    float acc0 = 0.f, acc1 = 0.f;
    #pragma unroll 8
    for (int d = 0; d < DIM; ++d) {
        float hv = hrow[d];
        acc0 += hv * W[d * DIM + lane];
        acc1 += hv * W[d * DIM + lane + 64];
    }
    atomicAdd(&out[(long long)dst * DIM + lane],      acc0 * w);
    atomicAdd(&out[(long long)dst * DIM + lane + 64], acc1 * w);
}

// ---------------------------------------------------------------------------
extern "C" void kernel_launch(void* const* d_in, const int* in_sizes, int n_in,
                              void* d_out, int out_size, void* d_ws, size_t ws_size,
                              hipStream_t stream)
{
    const float* x     = (const float*)d_in[0];
    const float* h     = (const float*)d_in[1];
    const int*   ei    = (const int*)  d_in[2];
    const int*   et    = (const int*)  d_in[3];
    const float* ew    = (const float*)d_in[4];
    const float* rel   = (const float*)d_in[5];
    const float* rootW = (const float*)d_in[6];
    const float* bias  = (const float*)d_in[7];
    const float* skipW = (const float*)d_in[8];
    const float* skipB = (const float*)d_in[9];
    float* out = (float*)d_out;

    const int N = in_sizes[0] / DIM;           // 50000
    const int E = in_sizes[3];                 // 600000
    const int R = in_sizes[5] / (DIM * DIM);   // 8

    // 1) out = bias + skip_bias + x@skipW^T + h@rootW
    base_kernel<<<dim3((N + BM - 1) / BM), 256, 0, stream>>>(
        x, h, skipW, rootW, bias, skipB, out, N);

    const size_t S_elems  = (size_t)N * 8 * DIM;
    const size_t need_new = S_elems * sizeof(float)
                          + ((size_t)(N + 1) + N + E) * sizeof(int);

    if (R == 8 && ws_size >= need_new) {
        float* S       = (float*)d_ws;
        int*   offsets = (int*)(S + S_elems);        // N+1
        int*   cursor  = offsets + (N + 1);          // N (aliases counts)
        int*   perm    = cursor + N;                 // E

        zero_i32_kernel<<<dim3((N + 255) / 256), 256, 0, stream>>>(cursor, N);
        hist_kernel<<<dim3((E + 255) / 256), 256, 0, stream>>>(ei, cursor, E);
        scan_kernel<<<1, 1024, 0, stream>>>(cursor, offsets, cursor, N, E);
        scatter_kernel<<<dim3((E + 255) / 256), 256, 0, stream>>>(ei, cursor, perm, E);
        accum_kernel<<<dim3((N + 3) / 4), 256, 0, stream>>>(
            ei, et, ew, h, offsets, perm, S, N, E);
        fuse_gemm_kernel<<<dim3((N + BM - 1) / BM), 256, 0, stream>>>(
            S, rel, out, N, 8 * DIM);
    } else if (ws_size >= (size_t)N * R * DIM * sizeof(float)) {
        float* hrel = (float*)d_ws;
        hrel_kernel<<<dim3((N + BM - 1) / BM, R), 256, 0, stream>>>(h, rel, hrel, N, R);
        edge_kernel<<<dim3((E + 7) / 8), 256, 0, stream>>>(ei, et, ew, hrel, out, E, R);
    } else {
        edge_direct_kernel<<<dim3((E + 3) / 4), 256, 0, stream>>>(ei, et, ew, h, rel, out, E);
    }
}

// Round 4
// 311.780 us; speedup vs baseline: 4.5303x; 2.0813x over previous
//
#include <hip/hip_runtime.h>

// RGCN layer with skip on MI355X.
// out[n] = bias + skip_bias + x[n]@skipW^T + h[n]@rootW + sum_{e: dst=n} ew[e]*(h[src]@rel[etype])
//
// Round 3: single fused bf16-MFMA GEMM  out = [S | h | x] @ [relF; rootW; skipW^T] + bb
//   - CSR-by-dst, sorted packed edge payloads (no perm indirection)
//   - accum: f32 accumulate, bf16 S (halved traffic), no float atomics
//   - MFMA 16x16x32 bf16, XOR-swizzled LDS, bias fused in epilogue

constexpr int DIM  = 128;
constexpr int BM   = 64;
constexpr int KC   = 32;
constexpr int BPAD = 4;
constexpr int KTOT = 1280;   // 8*128 (S) + 128 (h) + 128 (x)

typedef __attribute__((ext_vector_type(8))) short     short8v;
typedef __attribute__((ext_vector_type(8))) unsigned short ushort8v;
typedef __attribute__((ext_vector_type(4))) float     float4v;

__device__ __forceinline__ unsigned short f2bf(float x) {
    union { float f; unsigned u; } c; c.f = x;
    unsigned u = c.u;
    u += 0x7fffu + ((u >> 16) & 1u);   // round-to-nearest-even
    return (unsigned short)(u >> 16);
}

// ---------------------------------------------------------------------------
// CSR build
// ---------------------------------------------------------------------------
__global__ __launch_bounds__(256) void zero_i32_kernel(int* __restrict__ p, int n)
{
    int i = blockIdx.x * 256 + threadIdx.x;
    if (i < n) p[i] = 0;
}

__global__ __launch_bounds__(256) void hist_kernel(
    const int* __restrict__ ei, int* __restrict__ counts, int E)
{
    int e = blockIdx.x * 256 + threadIdx.x;
    if (e < E) atomicAdd(&counts[ei[(long long)E + e]], 1);
}

// single-block exclusive scan of counts[N] -> offsets[N+1]; cursor := offsets.
// counts and cursor alias (read-before-write per element).
__global__ __launch_bounds__(1024) void scan_kernel(
    const int* __restrict__ counts, int* __restrict__ offsets,
    int* __restrict__ cursor, int N, int E)
{
    __shared__ int sh[1024];
    const int t  = threadIdx.x;
    const int CH = (N + 1023) / 1024;

    int s = 0;
    for (int j = 0; j < CH; ++j) {
        int idx = t * CH + j;
        if (idx < N) s += counts[idx];
    }
    sh[t] = s;
    __syncthreads();
    for (int off = 1; off < 1024; off <<= 1) {
        int v = (t >= off) ? sh[t - off] : 0;
        __syncthreads();
        sh[t] += v;
        __syncthreads();
    }
    int base = sh[t] - s;
    for (int j = 0; j < CH; ++j) {
        int idx = t * CH + j;
        if (idx < N) {
            int c = counts[idx];
            offsets[idx] = base;
            cursor[idx]  = base;
            base += c;
        }
    }
    if (t == 1023) offsets[N] = E;
}

// sort edge payloads by dst: spack[pos] = (src<<3)|type, sw[pos] = weight
__global__ __launch_bounds__(256) void scatter_kernel(
    const int* __restrict__ ei, const int* __restrict__ et,
    const float* __restrict__ ew, int* __restrict__ cursor,
    int* __restrict__ spack, float* __restrict__ sw, int E)
{
    int e = blockIdx.x * 256 + threadIdx.x;
    if (e < E) {
        int pos = atomicAdd(&cursor[ei[(long long)E + e]], 1);
        spack[pos] = (ei[e] << 3) | (et[e] & 7);
        sw[pos]    = ew[e];
    }
}

// ---------------------------------------------------------------------------
// one wave per dst node: S[n, r*128+:] = sum_{e in bucket(n), type=r} ew[e]*h[src,:]
// f32 accumulate, bf16 store. Edge loop unrolled x2 to overlap gathers.
// ---------------------------------------------------------------------------
__global__ __launch_bounds__(256) void accum_kernel(
    const int* __restrict__ spack, const float* __restrict__ sw,
    const float* __restrict__ h, const int* __restrict__ offsets,
    unsigned short* __restrict__ S, int N)
{
    const int n    = blockIdx.x * 4 + (threadIdx.x >> 6);
    const int lane = threadIdx.x & 63;
    if (n >= N) return;

    const int start = offsets[n];
    const int end   = offsets[n + 1];

    float2 acc[8];
    #pragma unroll
    for (int rr = 0; rr < 8; ++rr) acc[rr] = make_float2(0.f, 0.f);

    int o = start;
    for (; o + 2 <= end; o += 2) {
        const int   p0 = spack[o],     p1 = spack[o + 1];
        const float w0 = sw[o],        w1 = sw[o + 1];
        const float2 h0 = *reinterpret_cast<const float2*>(
            h + (size_t)(p0 >> 3) * DIM + lane * 2);
        const float2 h1 = *reinterpret_cast<const float2*>(
            h + (size_t)(p1 >> 3) * DIM + lane * 2);
        const int r0 = p0 & 7, r1 = p1 & 7;
        #pragma unroll
        for (int rr = 0; rr < 8; ++rr) {
            const float m0 = (rr == r0) ? w0 : 0.f;
            const float m1 = (rr == r1) ? w1 : 0.f;
            acc[rr].x += m0 * h0.x + m1 * h1.x;
            acc[rr].y += m0 * h0.y + m1 * h1.y;
        }
    }
    if (o < end) {
        const int   p0 = spack[o];
        const float w0 = sw[o];
        const float2 h0 = *reinterpret_cast<const float2*>(
            h + (size_t)(p0 >> 3) * DIM + lane * 2);
        const int r0 = p0 & 7;
        #pragma unroll
        for (int rr = 0; rr < 8; ++rr) {
            const float m0 = (rr == r0) ? w0 : 0.f;
            acc[rr].x += m0 * h0.x;
            acc[rr].y += m0 * h0.y;
        }
    }

    #pragma unroll
    for (int rr = 0; rr < 8; ++rr) {
        unsigned pk = (unsigned)f2bf(acc[rr].x) | ((unsigned)f2bf(acc[rr].y) << 16);
        *reinterpret_cast<unsigned*>(
            &S[(size_t)n * 1024 + rr * DIM + lane * 2]) = pk;
    }
}

// ---------------------------------------------------------------------------
// Bt[f][k] (bf16, k-major per output col): k<1024 -> relF[k][f];
// 1024..1151 -> rootW[k-1024][f]; 1152..1279 -> skipW[f][k-1152]
// ---------------------------------------------------------------------------
__global__ __launch_bounds__(256) void repack_B_kernel(
    const float* __restrict__ relF, const float* __restrict__ rootW,
    const float* __restrict__ skipW, unsigned short* __restrict__ Bt)
{
    int idx = blockIdx.x * 256 + threadIdx.x;
    if (idx >= DIM * KTOT) return;
    int f = idx / KTOT, k = idx % KTOT;
    float v;
    if (k < 1024)       v = relF[(size_t)k * DIM + f];
    else if (k < 1152)  v = rootW[(k - 1024) * DIM + f];
    else                v = skipW[f * DIM + (k - 1152)];
    Bt[(size_t)f * KTOT + k] = f2bf(v);
}

// ---------------------------------------------------------------------------
// out[n0+i][j] = sum_k A[i][k]*B[k][j] + bias[j] + skipB[j]
// A = [S(bf16) | h(f32->bf16) | x(f32->bf16)], B from Bt.
// 256 thr = 4 waves 2x2, 64x64 out each; BM=BN=128, BK=64; XOR-swizzled LDS.
// ---------------------------------------------------------------------------
__global__ __launch_bounds__(256) void mfma_gemm_kernel(
    const unsigned short* __restrict__ S, const float* __restrict__ h,
    const float* __restrict__ x, const unsigned short* __restrict__ Bt,
    const float* __restrict__ bias, const float* __restrict__ skipB,
    float* __restrict__ out, int N)
{
    __shared__ unsigned short As[128 * 64];   // [row][k] swizzled, 16 KiB
    __shared__ unsigned short Bs[128 * 64];   // [col][k] swizzled, 16 KiB

    const int tid  = threadIdx.x;
    const int lane = tid & 63;
    const int wid  = tid >> 6;
    const int wr   = wid >> 1, wc = wid & 1;
    const int l15  = lane & 15, l4 = lane >> 4;
    const int n0   = blockIdx.x * 128;

    float4v acc[4][4];
    #pragma unroll
    for (int m = 0; m < 4; ++m)
        #pragma unroll
        for (int nn = 0; nn < 4; ++nn)
            acc[m][nn] = (float4v)0.f;

    for (int k0 = 0; k0 < KTOT; k0 += 64) {
        __syncthreads();
        // ---- stage A tile [128 rows][64 k] ----
        if (k0 < 1024) {
            #pragma unroll
            for (int i = 0; i < 4; ++i) {
                int idx = tid + i * 256;          // 0..1023
                int row = idx >> 3, c8 = idx & 7;
                int n = n0 + row;
                ushort8v v = (ushort8v)0;
                if (n < N)
                    v = *reinterpret_cast<const ushort8v*>(
                        &S[(size_t)n * 1024 + k0 + c8 * 8]);
                int bo = row * 128 + ((c8 * 16) ^ ((row & 7) << 4));
                *reinterpret_cast<ushort8v*>((char*)As + bo) = v;
            }
        } else {
            const float* __restrict__ A = (k0 < 1152) ? h : x;
            const int kb = (k0 < 1152) ? (k0 - 1024) : (k0 - 1152);
            #pragma unroll
            for (int i = 0; i < 8; ++i) {
                int idx = tid + i * 256;          // 0..2047
                int row = idx >> 4, c4 = idx & 15;
                int n = n0 + row;
                float4 v = make_float4(0.f, 0.f, 0.f, 0.f);
                if (n < N)
                    v = *reinterpret_cast<const float4*>(
                        &A[(size_t)n * DIM + kb + c4 * 4]);
                unsigned short b4[4] = { f2bf(v.x), f2bf(v.y), f2bf(v.z), f2bf(v.w) };
                int bo = row * 128 + ((c4 * 8) ^ ((row & 7) << 4));
                *reinterpret_cast<ulonglong1*>((char*)As + bo) =
                    *reinterpret_cast<const ulonglong1*>(b4);
            }
        }
        // ---- stage B tile [128 cols][64 k] from Bt[f][KTOT] ----
        #pragma unroll
        for (int i = 0; i < 4; ++i) {
            int idx = tid + i * 256;              // 0..1023
            int col = idx >> 3, c8 = idx & 7;
            ushort8v v = *reinterpret_cast<const ushort8v*>(
                &Bt[(size_t)col * KTOT + k0 + c8 * 8]);
            int bo = col * 128 + ((c8 * 16) ^ ((col & 7) << 4));
            *reinterpret_cast<ushort8v*>((char*)Bs + bo) = v;
        }
        __syncthreads();

        // ---- MFMA: 2 sub-steps of K=32 ----
        #pragma unroll
        for (int s = 0; s < 2; ++s) {
            const int kk = s * 32 + l4 * 8;       // this lane's k start
            short8v a[4], b[4];
            #pragma unroll
            for (int m = 0; m < 4; ++m) {
                int row = wr * 64 + m * 16 + l15;
                int bo = row * 128 + ((kk * 2) ^ ((row & 7) << 4));
                a[m] = *reinterpret_cast<const short8v*>((const char*)As + bo);
            }
            #pragma unroll
            for (int nn = 0; nn < 4; ++nn) {
                int col = wc * 64 + nn * 16 + l15;
                int bo = col * 128 + ((kk * 2) ^ ((col & 7) << 4));
                b[nn] = *reinterpret_cast<const short8v*>((const char*)Bs + bo);
            }
            #pragma unroll
            for (int m = 0; m < 4; ++m)
                #pragma unroll
                for (int nn = 0; nn < 4; ++nn)
                    acc[m][nn] = __builtin_amdgcn_mfma_f32_16x16x32_bf16(
                        a[m], b[nn], acc[m][nn], 0, 0, 0);
        }
    }

    // ---- epilogue: out = acc + bias + skipB ----
    #pragma unroll
    for (int nn = 0; nn < 4; ++nn) {
        const int col = wc * 64 + nn * 16 + l15;
        const float bb = bias[col] + skipB[col];
        #pragma unroll
        for (int m = 0; m < 4; ++m) {
            #pragma unroll
            for (int j = 0; j < 4; ++j) {
                int row = wr * 64 + m * 16 + l4 * 4 + j;
                int n = n0 + row;
                if (n < N)
                    out[(size_t)n * DIM + col] = acc[m][nn][j] + bb;
            }
        }
    }
}

// ---------------------------------------------------------------------------
// fallback kernels (round 0/1) in case ws is too small or R != 8
// ---------------------------------------------------------------------------
__global__ __launch_bounds__(256) void base_kernel(
    const float* __restrict__ x, const float* __restrict__ h,
    const float* __restrict__ skipW, const float* __restrict__ rootW,
    const float* __restrict__ bias, const float* __restrict__ skipB,
    float* __restrict__ out, int N)
{
    __shared__ float As2[BM][KC];
    __shared__ float Bs2[KC][DIM + BPAD];

    const int tid = threadIdx.x;
    const int n0  = blockIdx.x * BM;
    const int f0  = (tid & 31) * 4;
    const int r0  = (tid >> 5) * 8;

    float acc[8][4] = {};

    for (int phase = 0; phase < 2; ++phase) {
        const float* __restrict__ A = phase ? h : x;
        for (int d0 = 0; d0 < DIM; d0 += KC) {
            __syncthreads();
            for (int idx = tid; idx < BM * KC; idx += 256) {
                int r = idx / KC, dd = idx % KC;
                int n = n0 + r;
                As2[r][dd] = (n < N) ? A[(long long)n * DIM + d0 + dd] : 0.f;
            }
            if (phase == 0) {
                for (int idx = tid; idx < DIM * KC; idx += 256) {
                    int f = idx / KC, dd = idx % KC;
                    Bs2[dd][f] = skipW[f * DIM + d0 + dd];
                }
            } else {
                for (int idx = tid; idx < KC * DIM; idx += 256) {
                    int dd = idx / DIM, f = idx % DIM;
                    Bs2[dd][f] = rootW[(d0 + dd) * DIM + f];
                }
            }
            __syncthreads();
            #pragma unroll
            for (int dd = 0; dd < KC; ++dd) {
                float a[8];
                #pragma unroll
                for (int i = 0; i < 8; ++i) a[i] = As2[r0 + i][dd];
                const float4 b = *reinterpret_cast<const float4*>(&Bs2[dd][f0]);
                #pragma unroll
                for (int i = 0; i < 8; ++i) {
                    acc[i][0] += a[i] * b.x; acc[i][1] += a[i] * b.y;
                    acc[i][2] += a[i] * b.z; acc[i][3] += a[i] * b.w;
                }
            }
        }
    }

    float bb[4];
    #pragma unroll
    for (int j = 0; j < 4; ++j) bb[j] = bias[f0 + j] + skipB[f0 + j];
    #pragma unroll
    for (int i = 0; i < 8; ++i) {
        int n = n0 + r0 + i;
        if (n < N) {
            float4 v = make_float4(acc[i][0] + bb[0], acc[i][1] + bb[1],
                                   acc[i][2] + bb[2], acc[i][3] + bb[3]);
            *reinterpret_cast<float4*>(&out[(long long)n * DIM + f0]) = v;
        }
    }
}

__global__ __launch_bounds__(256) void hrel_kernel(
    const float* __restrict__ h, const float* __restrict__ rel,
    float* __restrict__ hrel, int N, int R)
{
    __shared__ float As2[BM][KC];
    __shared__ float Bs2[KC][DIM + BPAD];

    const int tid = threadIdx.x;
    const int n0  = blockIdx.x * BM;
    const int rr  = blockIdx.y;
    const float* __restrict__ B = rel + (size_t)rr * DIM * DIM;
    const int f0  = (tid & 31) * 4;
    const int r0  = (tid >> 5) * 8;

    float acc[8][4] = {};

    for (int d0 = 0; d0 < DIM; d0 += KC) {
        __syncthreads();
        for (int idx = tid; idx < BM * KC; idx += 256) {
            int r = idx / KC, dd = idx % KC;
            int n = n0 + r;
            As2[r][dd] = (n < N) ? h[(long long)n * DIM + d0 + dd] : 0.f;
        }
        for (int idx = tid; idx < KC * DIM; idx += 256) {
            int dd = idx / DIM, f = idx % DIM;
            Bs2[dd][f] = B[(d0 + dd) * DIM + f];
        }
        __syncthreads();
        #pragma unroll
        for (int dd = 0; dd < KC; ++dd) {
            float a[8];
            #pragma unroll
            for (int i = 0; i < 8; ++i) a[i] = As2[r0 + i][dd];
            const float4 b = *reinterpret_cast<const float4*>(&Bs2[dd][f0]);
            #pragma unroll
            for (int i = 0; i < 8; ++i) {
                acc[i][0] += a[i] * b.x; acc[i][1] += a[i] * b.y;
                acc[i][2] += a[i] * b.z; acc[i][3] += a[i] * b.w;
            }
        }
    }

    #pragma unroll
    for (int i = 0; i < 8; ++i) {
        int n = n0 + r0 + i;
        if (n < N) {
            float4 v = make_float4(acc[i][0], acc[i][1], acc[i][2], acc[i][3]);
            *reinterpret_cast<float4*>(&hrel[((long long)n * R + rr) * DIM + f0]) = v;
        }
    }
}

__global__ __launch_bounds__(256) void edge_kernel(
    const int* __restrict__ ei, const int* __restrict__ et,
    const float* __restrict__ ew, const float* __restrict__ hrel,
    float* __restrict__ out, int E, int R)
{
    const int tid  = threadIdx.x;
    const int lane = tid & 31;
    const long long e = (long long)blockIdx.x * 8 + (tid >> 5);
    if (e >= E) return;

    const int   src = ei[e];
    const int   dst = ei[(long long)E + e];
    const int   r   = et[e];
    const float w   = ew[e];

    const float4 v = reinterpret_cast<const float4*>(
        hrel + ((long long)src * R + r) * DIM)[lane];

    float* o = out + (long long)dst * DIM + lane * 4;
    atomicAdd(o + 0, v.x * w);
    atomicAdd(o + 1, v.y * w);
    atomicAdd(o + 2, v.z * w);
    atomicAdd(o + 3, v.w * w);
}

__global__ __launch_bounds__(256) void edge_direct_kernel(
    const int* __restrict__ ei, const int* __restrict__ et,
    const float* __restrict__ ew, const float* __restrict__ h,
    const float* __restrict__ rel, float* __restrict__ out, int E)
{
    const int wid  = threadIdx.x >> 6;
    const int lane = threadIdx.x & 63;
    const long long e = (long long)blockIdx.x * 4 + wid;
    if (e >= E) return;

    const int   src = ei[e];
    const int   dst = ei[(long long)E + e];
    const int   r   = et[e];
    const float w   = ew[e];

    const float* __restrict__ hrow = h + (long long)src * DIM;
    const float* __restrict__ W    = rel + (size_t)r * DIM * DIM;

    float acc0 = 0.f, acc1 = 0.f;
    #pragma unroll 8
    for (int d = 0; d < DIM; ++d) {
        float hv = hrow[d];
        acc0 += hv * W[d * DIM + lane];
        acc1 += hv * W[d * DIM + lane + 64];
    }
    atomicAdd(&out[(long long)dst * DIM + lane],      acc0 * w);
    atomicAdd(&out[(long long)dst * DIM + lane + 64], acc1 * w);
}

// ---------------------------------------------------------------------------
extern "C" void kernel_launch(void* const* d_in, const int* in_sizes, int n_in,
                              void* d_out, int out_size, void* d_ws, size_t ws_size,
                              hipStream_t stream)
{
    const float* x     = (const float*)d_in[0];
    const float* h     = (const float*)d_in[1];
    const int*   ei    = (const int*)  d_in[2];
    const int*   et    = (const int*)  d_in[3];
    const float* ew    = (const float*)d_in[4];
    const float* rel   = (const float*)d_in[5];
    const float* rootW = (const float*)d_in[6];
    const float* bias  = (const float*)d_in[7];
    const float* skipW = (const float*)d_in[8];
    const float* skipB = (const float*)d_in[9];
    float* out = (float*)d_out;

    const int N = in_sizes[0] / DIM;           // 50000
    const int E = in_sizes[3];                 // 600000
    const int R = in_sizes[5] / (DIM * DIM);   // 8

    // workspace layout
    const size_t S_elems  = (size_t)N * 1024;          // bf16
    const size_t Bt_elems = (size_t)DIM * KTOT;        // bf16
    const size_t need_new = S_elems * 2 + Bt_elems * 2
                          + ((size_t)(N + 1) + N + E) * sizeof(int)
                          + (size_t)E * sizeof(float);

    if (R == 8 && ws_size >= need_new) {
        unsigned short* S  = (unsigned short*)d_ws;
        unsigned short* Bt = S + S_elems;
        int*   offsets = (int*)(Bt + Bt_elems);        // N+1
        int*   cursor  = offsets + (N + 1);            // N (aliases counts)
        int*   spack   = cursor + N;                   // E
        float* sw      = (float*)(spack + E);          // E

        zero_i32_kernel<<<dim3((N + 255) / 256), 256, 0, stream>>>(cursor, N);
        hist_kernel<<<dim3((E + 255) / 256), 256, 0, stream>>>(ei, cursor, E);
        scan_kernel<<<1, 1024, 0, stream>>>(cursor, offsets, cursor, N, E);
        scatter_kernel<<<dim3((E + 255) / 256), 256, 0, stream>>>(
            ei, et, ew, cursor, spack, sw, E);
        repack_B_kernel<<<dim3((DIM * KTOT + 255) / 256), 256, 0, stream>>>(
            rel, rootW, skipW, Bt);
        accum_kernel<<<dim3((N + 3) / 4), 256, 0, stream>>>(
            spack, sw, h, offsets, S, N);
        mfma_gemm_kernel<<<dim3((N + 127) / 128), 256, 0, stream>>>(
            S, h, x, Bt, bias, skipB, out, N);
    } else {
        base_kernel<<<dim3((N + BM - 1) / BM), 256, 0, stream>>>(
            x, h, skipW, rootW, bias, skipB, out, N);
        if (ws_size >= (size_t)N * R * DIM * sizeof(float)) {
            float* hrel = (float*)d_ws;
            hrel_kernel<<<dim3((N + BM - 1) / BM, R), 256, 0, stream>>>(h, rel, hrel, N, R);
            edge_kernel<<<dim3((E + 7) / 8), 256, 0, stream>>>(ei, et, ew, hrel, out, E, R);
        } else {
            edge_direct_kernel<<<dim3((E + 3) / 4), 256, 0, stream>>>(ei, et, ew, h, rel, out, E);
        }
    }
}

// Round 5
// 200.329 us; speedup vs baseline: 7.0506x; 1.5563x over previous
//
#include <hip/hip_runtime.h>

// RGCN layer with skip on MI355X.
// out[n] = bias + skip_bias + x[n]@skipW^T + h[n]@rootW + sum_{e: dst=n} ew[e]*(h[src]@rel[etype])
//
// Round 4: single fused bf16-MFMA GEMM  out = [S | h | x] @ [relF; rootW; skipW^T] + bb
//   + hierarchical 3-kernel scan (round-3's single-block scan was 124 us on 1 CU)

constexpr int DIM  = 128;
constexpr int BM   = 64;
constexpr int KC   = 32;
constexpr int BPAD = 4;
constexpr int KTOT = 1280;        // 8*128 (S) + 128 (h) + 128 (x)
constexpr int SCAN_CHUNK = 2048;  // elements per scan block (256 thr x 8)

typedef __attribute__((ext_vector_type(8))) short     short8v;
typedef __attribute__((ext_vector_type(8))) unsigned short ushort8v;
typedef __attribute__((ext_vector_type(4))) float     float4v;

__device__ __forceinline__ unsigned short f2bf(float x) {
    union { float f; unsigned u; } c; c.f = x;
    unsigned u = c.u;
    u += 0x7fffu + ((u >> 16) & 1u);   // round-to-nearest-even
    return (unsigned short)(u >> 16);
}

// ---------------------------------------------------------------------------
// CSR build
// ---------------------------------------------------------------------------
__global__ __launch_bounds__(256) void zero_i32_kernel(int* __restrict__ p, int n)
{
    int i = blockIdx.x * 256 + threadIdx.x;
    if (i < n) p[i] = 0;
}

__global__ __launch_bounds__(256) void hist_kernel(
    const int* __restrict__ ei, int* __restrict__ counts, int E)
{
    int e = blockIdx.x * 256 + threadIdx.x;
    if (e < E) atomicAdd(&counts[ei[(long long)E + e]], 1);
}

// --- hierarchical exclusive scan of counts[N] -> offsets[N+1], cursor := offsets
// scan1: per-block local exclusive scan (2048 elems/block) + block totals
__global__ __launch_bounds__(256) void scan1_kernel(
    const int* __restrict__ counts, int* __restrict__ local,
    int* __restrict__ blockSums, int N)
{
    __shared__ int sh[256];
    const int b = blockIdx.x, t = threadIdx.x;
    const int base = b * SCAN_CHUNK + t * 8;

    int v[8];
    int s = 0;
    #pragma unroll
    for (int j = 0; j < 8; ++j) {
        int idx = base + j;
        v[j] = (idx < N) ? counts[idx] : 0;
        s += v[j];
    }
    sh[t] = s;
    __syncthreads();
    for (int off = 1; off < 256; off <<= 1) {
        int x = (t >= off) ? sh[t - off] : 0;
        __syncthreads();
        sh[t] += x;
        __syncthreads();
    }
    int ex = sh[t] - s;                       // exclusive prefix of this thread
    if (t == 255) blockSums[b] = sh[255];     // block total
    #pragma unroll
    for (int j = 0; j < 8; ++j) {
        int idx = base + j;
        if (idx < N) { local[idx] = ex; ex += v[j]; }
    }
}

// scan2: single small block scans the block totals (nb <= 1024), exclusive in place
__global__ __launch_bounds__(1024) void scan2_kernel(int* __restrict__ bs, int nb)
{
    __shared__ int sh[1024];
    const int t = threadIdx.x;
    int v = (t < nb) ? bs[t] : 0;
    sh[t] = v;
    __syncthreads();
    for (int off = 1; off < 1024; off <<= 1) {
        int x = (t >= off) ? sh[t - off] : 0;
        __syncthreads();
        sh[t] += x;
        __syncthreads();
    }
    if (t < nb) bs[t] = sh[t] - v;
}

// scan3: add block offset; emit offsets and cursor; offsets[N] = E
__global__ __launch_bounds__(256) void scan3_kernel(
    int* __restrict__ offsets, const int* __restrict__ blockSums,
    int* __restrict__ cursor, int N, int E)
{
    const int b = blockIdx.x, t = threadIdx.x;
    const int add = blockSums[b];
    #pragma unroll
    for (int j = 0; j < 8; ++j) {
        int idx = b * SCAN_CHUNK + j * 256 + t;
        if (idx < N) {
            int v = offsets[idx] + add;
            offsets[idx] = v;
            cursor[idx]  = v;
        }
    }
    if (b == 0 && t == 0) offsets[N] = E;
}

// sort edge payloads by dst: spack[pos] = (src<<3)|type, sw[pos] = weight
__global__ __launch_bounds__(256) void scatter_kernel(
    const int* __restrict__ ei, const int* __restrict__ et,
    const float* __restrict__ ew, int* __restrict__ cursor,
    int* __restrict__ spack, float* __restrict__ sw, int E)
{
    int e = blockIdx.x * 256 + threadIdx.x;
    if (e < E) {
        int pos = atomicAdd(&cursor[ei[(long long)E + e]], 1);
        spack[pos] = (ei[e] << 3) | (et[e] & 7);
        sw[pos]    = ew[e];
    }
}

// ---------------------------------------------------------------------------
// one wave per dst node: S[n, r*128+:] = sum_{e in bucket(n), type=r} ew[e]*h[src,:]
// f32 accumulate, bf16 store. Edge loop unrolled x2 to overlap gathers.
// ---------------------------------------------------------------------------
__global__ __launch_bounds__(256) void accum_kernel(
    const int* __restrict__ spack, const float* __restrict__ sw,
    const float* __restrict__ h, const int* __restrict__ offsets,
    unsigned short* __restrict__ S, int N)
{
    const int n    = blockIdx.x * 4 + (threadIdx.x >> 6);
    const int lane = threadIdx.x & 63;
    if (n >= N) return;

    const int start = offsets[n];
    const int end   = offsets[n + 1];

    float2 acc[8];
    #pragma unroll
    for (int rr = 0; rr < 8; ++rr) acc[rr] = make_float2(0.f, 0.f);

    int o = start;
    for (; o + 2 <= end; o += 2) {
        const int   p0 = spack[o],     p1 = spack[o + 1];
        const float w0 = sw[o],        w1 = sw[o + 1];
        const float2 h0 = *reinterpret_cast<const float2*>(
            h + (size_t)(p0 >> 3) * DIM + lane * 2);
        const float2 h1 = *reinterpret_cast<const float2*>(
            h + (size_t)(p1 >> 3) * DIM + lane * 2);
        const int r0 = p0 & 7, r1 = p1 & 7;
        #pragma unroll
        for (int rr = 0; rr < 8; ++rr) {
            const float m0 = (rr == r0) ? w0 : 0.f;
            const float m1 = (rr == r1) ? w1 : 0.f;
            acc[rr].x += m0 * h0.x + m1 * h1.x;
            acc[rr].y += m0 * h0.y + m1 * h1.y;
        }
    }
    if (o < end) {
        const int   p0 = spack[o];
        const float w0 = sw[o];
        const float2 h0 = *reinterpret_cast<const float2*>(
            h + (size_t)(p0 >> 3) * DIM + lane * 2);
        const int r0 = p0 & 7;
        #pragma unroll
        for (int rr = 0; rr < 8; ++rr) {
            const float m0 = (rr == r0) ? w0 : 0.f;
            acc[rr].x += m0 * h0.x;
            acc[rr].y += m0 * h0.y;
        }
    }

    #pragma unroll
    for (int rr = 0; rr < 8; ++rr) {
        unsigned pk = (unsigned)f2bf(acc[rr].x) | ((unsigned)f2bf(acc[rr].y) << 16);
        *reinterpret_cast<unsigned*>(
            &S[(size_t)n * 1024 + rr * DIM + lane * 2]) = pk;
    }
}

// ---------------------------------------------------------------------------
// Bt[f][k] (bf16, k-major per output col): k<1024 -> relF[k][f];
// 1024..1151 -> rootW[k-1024][f]; 1152..1279 -> skipW[f][k-1152]
// ---------------------------------------------------------------------------
__global__ __launch_bounds__(256) void repack_B_kernel(
    const float* __restrict__ relF, const float* __restrict__ rootW,
    const float* __restrict__ skipW, unsigned short* __restrict__ Bt)
{
    int idx = blockIdx.x * 256 + threadIdx.x;
    if (idx >= DIM * KTOT) return;
    int f = idx / KTOT, k = idx % KTOT;
    float v;
    if (k < 1024)       v = relF[(size_t)k * DIM + f];
    else if (k < 1152)  v = rootW[(k - 1024) * DIM + f];
    else                v = skipW[f * DIM + (k - 1152)];
    Bt[(size_t)f * KTOT + k] = f2bf(v);
}

// ---------------------------------------------------------------------------
// out[n0+i][j] = sum_k A[i][k]*B[k][j] + bias[j] + skipB[j]
// A = [S(bf16) | h(f32->bf16) | x(f32->bf16)], B from Bt.
// 256 thr = 4 waves 2x2, 64x64 out each; BM=BN=128, BK=64; XOR-swizzled LDS.
// ---------------------------------------------------------------------------
__global__ __launch_bounds__(256) void mfma_gemm_kernel(
    const unsigned short* __restrict__ S, const float* __restrict__ h,
    const float* __restrict__ x, const unsigned short* __restrict__ Bt,
    const float* __restrict__ bias, const float* __restrict__ skipB,
    float* __restrict__ out, int N)
{
    __shared__ unsigned short As[128 * 64];   // [row][k] swizzled, 16 KiB
    __shared__ unsigned short Bs[128 * 64];   // [col][k] swizzled, 16 KiB

    const int tid  = threadIdx.x;
    const int lane = tid & 63;
    const int wid  = tid >> 6;
    const int wr   = wid >> 1, wc = wid & 1;
    const int l15  = lane & 15, l4 = lane >> 4;
    const int n0   = blockIdx.x * 128;

    float4v acc[4][4];
    #pragma unroll
    for (int m = 0; m < 4; ++m)
        #pragma unroll
        for (int nn = 0; nn < 4; ++nn)
            acc[m][nn] = (float4v)0.f;

    for (int k0 = 0; k0 < KTOT; k0 += 64) {
        __syncthreads();
        // ---- stage A tile [128 rows][64 k] ----
        if (k0 < 1024) {
            #pragma unroll
            for (int i = 0; i < 4; ++i) {
                int idx = tid + i * 256;          // 0..1023
                int row = idx >> 3, c8 = idx & 7;
                int n = n0 + row;
                ushort8v v = (ushort8v)0;
                if (n < N)
                    v = *reinterpret_cast<const ushort8v*>(
                        &S[(size_t)n * 1024 + k0 + c8 * 8]);
                int bo = row * 128 + ((c8 * 16) ^ ((row & 7) << 4));
                *reinterpret_cast<ushort8v*>((char*)As + bo) = v;
            }
        } else {
            const float* __restrict__ A = (k0 < 1152) ? h : x;
            const int kb = (k0 < 1152) ? (k0 - 1024) : (k0 - 1152);
            #pragma unroll
            for (int i = 0; i < 8; ++i) {
                int idx = tid + i * 256;          // 0..2047
                int row = idx >> 4, c4 = idx & 15;
                int n = n0 + row;
                float4 v = make_float4(0.f, 0.f, 0.f, 0.f);
                if (n < N)
                    v = *reinterpret_cast<const float4*>(
                        &A[(size_t)n * DIM + kb + c4 * 4]);
                unsigned short b4[4] = { f2bf(v.x), f2bf(v.y), f2bf(v.z), f2bf(v.w) };
                int bo = row * 128 + ((c4 * 8) ^ ((row & 7) << 4));
                *reinterpret_cast<ulonglong1*>((char*)As + bo) =
                    *reinterpret_cast<const ulonglong1*>(b4);
            }
        }
        // ---- stage B tile [128 cols][64 k] from Bt[f][KTOT] ----
        #pragma unroll
        for (int i = 0; i < 4; ++i) {
            int idx = tid + i * 256;              // 0..1023
            int col = idx >> 3, c8 = idx & 7;
            ushort8v v = *reinterpret_cast<const ushort8v*>(
                &Bt[(size_t)col * KTOT + k0 + c8 * 8]);
            int bo = col * 128 + ((c8 * 16) ^ ((col & 7) << 4));
            *reinterpret_cast<ushort8v*>((char*)Bs + bo) = v;
        }
        __syncthreads();

        // ---- MFMA: 2 sub-steps of K=32 ----
        #pragma unroll
        for (int s = 0; s < 2; ++s) {
            const int kk = s * 32 + l4 * 8;       // this lane's k start
            short8v a[4], b[4];
            #pragma unroll
            for (int m = 0; m < 4; ++m) {
                int row = wr * 64 + m * 16 + l15;
                int bo = row * 128 + ((kk * 2) ^ ((row & 7) << 4));
                a[m] = *reinterpret_cast<const short8v*>((const char*)As + bo);
            }
            #pragma unroll
            for (int nn = 0; nn < 4; ++nn) {
                int col = wc * 64 + nn * 16 + l15;
                int bo = col * 128 + ((kk * 2) ^ ((col & 7) << 4));
                b[nn] = *reinterpret_cast<const short8v*>((const char*)Bs + bo);
            }
            #pragma unroll
            for (int m = 0; m < 4; ++m)
                #pragma unroll
                for (int nn = 0; nn < 4; ++nn)
                    acc[m][nn] = __builtin_amdgcn_mfma_f32_16x16x32_bf16(
                        a[m], b[nn], acc[m][nn], 0, 0, 0);
        }
    }

    // ---- epilogue: out = acc + bias + skipB ----
    #pragma unroll
    for (int nn = 0; nn < 4; ++nn) {
        const int col = wc * 64 + nn * 16 + l15;
        const float bb = bias[col] + skipB[col];
        #pragma unroll
        for (int m = 0; m < 4; ++m) {
            #pragma unroll
            for (int j = 0; j < 4; ++j) {
                int row = wr * 64 + m * 16 + l4 * 4 + j;
                int n = n0 + row;
                if (n < N)
                    out[(size_t)n * DIM + col] = acc[m][nn][j] + bb;
            }
        }
    }
}

// ---------------------------------------------------------------------------
// fallback kernels (round 0/1) in case ws is too small or R != 8
// ---------------------------------------------------------------------------
__global__ __launch_bounds__(256) void base_kernel(
    const float* __restrict__ x, const float* __restrict__ h,
    const float* __restrict__ skipW, const float* __restrict__ rootW,
    const float* __restrict__ bias, const float* __restrict__ skipB,
    float* __restrict__ out, int N)
{
    __shared__ float As2[BM][KC];
    __shared__ float Bs2[KC][DIM + BPAD];

    const int tid = threadIdx.x;
    const int n0  = blockIdx.x * BM;
    const int f0  = (tid & 31) * 4;
    const int r0  = (tid >> 5) * 8;

    float acc[8][4] = {};

    for (int phase = 0; phase < 2; ++phase) {
        const float* __restrict__ A = phase ? h : x;
        for (int d0 = 0; d0 < DIM; d0 += KC) {
            __syncthreads();
            for (int idx = tid; idx < BM * KC; idx += 256) {
                int r = idx / KC, dd = idx % KC;
                int n = n0 + r;
                As2[r][dd] = (n < N) ? A[(long long)n * DIM + d0 + dd] : 0.f;
            }
            if (phase == 0) {
                for (int idx = tid; idx < DIM * KC; idx += 256) {
                    int f = idx / KC, dd = idx % KC;
                    Bs2[dd][f] = skipW[f * DIM + d0 + dd];
                }
            } else {
                for (int idx = tid; idx < KC * DIM; idx += 256) {
                    int dd = idx / DIM, f = idx % DIM;
                    Bs2[dd][f] = rootW[(d0 + dd) * DIM + f];
                }
            }
            __syncthreads();
            #pragma unroll
            for (int dd = 0; dd < KC; ++dd) {
                float a[8];
                #pragma unroll
                for (int i = 0; i < 8; ++i) a[i] = As2[r0 + i][dd];
                const float4 b = *reinterpret_cast<const float4*>(&Bs2[dd][f0]);
                #pragma unroll
                for (int i = 0; i < 8; ++i) {
                    acc[i][0] += a[i] * b.x; acc[i][1] += a[i] * b.y;
                    acc[i][2] += a[i] * b.z; acc[i][3] += a[i] * b.w;
                }
            }
        }
    }

    float bb[4];
    #pragma unroll
    for (int j = 0; j < 4; ++j) bb[j] = bias[f0 + j] + skipB[f0 + j];
    #pragma unroll
    for (int i = 0; i < 8; ++i) {
        int n = n0 + r0 + i;
        if (n < N) {
            float4 v = make_float4(acc[i][0] + bb[0], acc[i][1] + bb[1],
                                   acc[i][2] + bb[2], acc[i][3] + bb[3]);
            *reinterpret_cast<float4*>(&out[(long long)n * DIM + f0]) = v;
        }
    }
}

__global__ __launch_bounds__(256) void hrel_kernel(
    const float* __restrict__ h, const float* __restrict__ rel,
    float* __restrict__ hrel, int N, int R)
{
    __shared__ float As2[BM][KC];
    __shared__ float Bs2[KC][DIM + BPAD];

    const int tid = threadIdx.x;
    const int n0  = blockIdx.x * BM;
    const int rr  = blockIdx.y;
    const float* __restrict__ B = rel + (size_t)rr * DIM * DIM;
    const int f0  = (tid & 31) * 4;
    const int r0  = (tid >> 5) * 8;

    float acc[8][4] = {};

    for (int d0 = 0; d0 < DIM; d0 += KC) {
        __syncthreads();
        for (int idx = tid; idx < BM * KC; idx += 256) {
            int r = idx / KC, dd = idx % KC;
            int n = n0 + r;
            As2[r][dd] = (n < N) ? h[(long long)n * DIM + d0 + dd] : 0.f;
        }
        for (int idx = tid; idx < KC * DIM; idx += 256) {
            int dd = idx / DIM, f = idx % DIM;
            Bs2[dd][f] = B[(d0 + dd) * DIM + f];
        }
        __syncthreads();
        #pragma unroll
        for (int dd = 0; dd < KC; ++dd) {
            float a[8];
            #pragma unroll
            for (int i = 0; i < 8; ++i) a[i] = As2[r0 + i][dd];
            const float4 b = *reinterpret_cast<const float4*>(&Bs2[dd][f0]);
            #pragma unroll
            for (int i = 0; i < 8; ++i) {
                acc[i][0] += a[i] * b.x; acc[i][1] += a[i] * b.y;
                acc[i][2] += a[i] * b.z; acc[i][3] += a[i] * b.w;
            }
        }
    }

    #pragma unroll
    for (int i = 0; i < 8; ++i) {
        int n = n0 + r0 + i;
        if (n < N) {
            float4 v = make_float4(acc[i][0], acc[i][1], acc[i][2], acc[i][3]);
            *reinterpret_cast<float4*>(&hrel[((long long)n * R + rr) * DIM + f0]) = v;
        }
    }
}

__global__ __launch_bounds__(256) void edge_kernel(
    const int* __restrict__ ei, const int* __restrict__ et,
    const float* __restrict__ ew, const float* __restrict__ hrel,
    float* __restrict__ out, int E, int R)
{
    const int tid  = threadIdx.x;
    const int lane = tid & 31;
    const long long e = (long long)blockIdx.x * 8 + (tid >> 5);
    if (e >= E) return;

    const int   src = ei[e];
    const int   dst = ei[(long long)E + e];
    const int   r   = et[e];
    const float w   = ew[e];

    const float4 v = reinterpret_cast<const float4*>(
        hrel + ((long long)src * R + r) * DIM)[lane];

    float* o = out + (long long)dst * DIM + lane * 4;
    atomicAdd(o + 0, v.x * w);
    atomicAdd(o + 1, v.y * w);
    atomicAdd(o + 2, v.z * w);
    atomicAdd(o + 3, v.w * w);
}

__global__ __launch_bounds__(256) void edge_direct_kernel(
    const int* __restrict__ ei, const int* __restrict__ et,
    const float* __restrict__ ew, const float* __restrict__ h,
    const float* __restrict__ rel, float* __restrict__ out, int E)
{
    const int wid  = threadIdx.x >> 6;
    const int lane = threadIdx.x & 63;
    const long long e = (long long)blockIdx.x * 4 + wid;
    if (e >= E) return;

    const int   src = ei[e];
    const int   dst = ei[(long long)E + e];
    const int   r   = et[e];
    const float w   = ew[e];

    const float* __restrict__ hrow = h + (long long)src * DIM;
    const float* __restrict__ W    = rel + (size_t)r * DIM * DIM;

    float acc0 = 0.f, acc1 = 0.f;
    #pragma unroll 8
    for (int d = 0; d < DIM; ++d) {
        float hv = hrow[d];
        acc0 += hv * W[d * DIM + lane];
        acc1 += hv * W[d * DIM + lane + 64];
    }
    atomicAdd(&out[(long long)dst * DIM + lane],      acc0 * w);
    atomicAdd(&out[(long long)dst * DIM + lane + 64], acc1 * w);
}

// ---------------------------------------------------------------------------
extern "C" void kernel_launch(void* const* d_in, const int* in_sizes, int n_in,
                              void* d_out, int out_size, void* d_ws, size_t ws_size,
                              hipStream_t stream)
{
    const float* x     = (const float*)d_in[0];
    const float* h     = (const float*)d_in[1];
    const int*   ei    = (const int*)  d_in[2];
    const int*   et    = (const int*)  d_in[3];
    const float* ew    = (const float*)d_in[4];
    const float* rel   = (const float*)d_in[5];
    const float* rootW = (const float*)d_in[6];
    const float* bias  = (const float*)d_in[7];
    const float* skipW = (const float*)d_in[8];
    const float* skipB = (const float*)d_in[9];
    float* out = (float*)d_out;

    const int N = in_sizes[0] / DIM;           // 50000
    const int E = in_sizes[3];                 // 600000
    const int R = in_sizes[5] / (DIM * DIM);   // 8

    const int nbScan = (N + SCAN_CHUNK - 1) / SCAN_CHUNK;

    // workspace layout
    const size_t S_elems  = (size_t)N * 1024;          // bf16
    const size_t Bt_elems = (size_t)DIM * KTOT;        // bf16
    const size_t need_new = S_elems * 2 + Bt_elems * 2
                          + ((size_t)(N + 1) + N + 1024 + E) * sizeof(int)
                          + (size_t)E * sizeof(float);

    if (R == 8 && nbScan <= 1024 && ws_size >= need_new) {
        unsigned short* S  = (unsigned short*)d_ws;
        unsigned short* Bt = S + S_elems;
        int*   offsets   = (int*)(Bt + Bt_elems);      // N+1
        int*   cursor    = offsets + (N + 1);          // N (counts, then cursor)
        int*   blockSums = cursor + N;                 // 1024
        int*   spack     = blockSums + 1024;           // E
        float* sw        = (float*)(spack + E);        // E

        zero_i32_kernel<<<dim3((N + 255) / 256), 256, 0, stream>>>(cursor, N);
        hist_kernel<<<dim3((E + 255) / 256), 256, 0, stream>>>(ei, cursor, E);
        scan1_kernel<<<dim3(nbScan), 256, 0, stream>>>(cursor, offsets, blockSums, N);
        scan2_kernel<<<dim3(1), 1024, 0, stream>>>(blockSums, nbScan);
        scan3_kernel<<<dim3(nbScan), 256, 0, stream>>>(offsets, blockSums, cursor, N, E);
        scatter_kernel<<<dim3((E + 255) / 256), 256, 0, stream>>>(
            ei, et, ew, cursor, spack, sw, E);
        repack_B_kernel<<<dim3((DIM * KTOT + 255) / 256), 256, 0, stream>>>(
            rel, rootW, skipW, Bt);
        accum_kernel<<<dim3((N + 3) / 4), 256, 0, stream>>>(
            spack, sw, h, offsets, S, N);
        mfma_gemm_kernel<<<dim3((N + 127) / 128), 256, 0, stream>>>(
            S, h, x, Bt, bias, skipB, out, N);
    } else {
        base_kernel<<<dim3((N + BM - 1) / BM), 256, 0, stream>>>(
            x, h, skipW, rootW, bias, skipB, out, N);
        if (ws_size >= (size_t)N * R * DIM * sizeof(float)) {
            float* hrel = (float*)d_ws;
            hrel_kernel<<<dim3((N + BM - 1) / BM, R), 256, 0, stream>>>(h, rel, hrel, N, R);
            edge_kernel<<<dim3((E + 7) / 8), 256, 0, stream>>>(ei, et, ew, hrel, out, E, R);
        } else {
            edge_direct_kernel<<<dim3((E + 3) / 4), 256, 0, stream>>>(ei, et, ew, h, rel, out, E);
        }
    }
}